// Round 3
// baseline (917.203 us; speedup 1.0000x reference)
//
#include <hip/hip_runtime.h>
#include <hip/hip_bf16.h>

#define T_TOK 4096
#define DIM   1024
#define FDIM  4096
#define NEXP  8
#define BM    128
#define BK    32
#define BN_A  64
#define BN_B  128

typedef __attribute__((ext_vector_type(8))) short bf16x8_t;   // 8 bf16 = 4 VGPR
typedef __attribute__((ext_vector_type(4))) float f32x4_t;    // MFMA C/D

// async global->LDS, 16B per lane; LDS dest = wave-uniform base + lane*16
#define GLD16(gp, lp) __builtin_amdgcn_global_load_lds( \
    (const __attribute__((address_space(1))) unsigned int*)(gp), \
    (__attribute__((address_space(3))) unsigned int*)(lp), 16, 0, 0)

__device__ __forceinline__ unsigned short f2bf(float f) {
    union { __hip_bfloat16 h; unsigned short u; } c;
    c.h = __float2bfloat16(f);
    return c.u;
}
__device__ __forceinline__ uint4 pack8(const float4& a, const float4& b) {
    union { unsigned short s[8]; uint4 v; } u;
    u.s[0] = f2bf(a.x); u.s[1] = f2bf(a.y); u.s[2] = f2bf(a.z); u.s[3] = f2bf(a.w);
    u.s[4] = f2bf(b.x); u.s[5] = f2bf(b.y); u.s[6] = f2bf(b.z); u.s[7] = f2bf(b.w);
    return u.v;
}

// ---------------------------------------------------------------------------
// 1. Gate: one wave per token. fp32 logits, top-2, renormalized weights.
// ---------------------------------------------------------------------------
__global__ __launch_bounds__(256) void gate_kernel(
    const float* __restrict__ x, const float* __restrict__ gw,
    const float* __restrict__ gb, int* __restrict__ cnt,
    int* __restrict__ toklist, float* __restrict__ wlist)
{
    const int lane = threadIdx.x & 63;
    const int wv   = threadIdx.x >> 6;
    const int t    = blockIdx.x * 4 + wv;
    const float* xr = x + (size_t)t * DIM;

    float4 xv[4];
#pragma unroll
    for (int c = 0; c < 4; ++c)
        xv[c] = *reinterpret_cast<const float4*>(xr + c * 256 + lane * 4);

    float logit[NEXP];
#pragma unroll
    for (int e = 0; e < NEXP; ++e) {
        const float* gr = gw + e * DIM;
        float s = 0.f;
#pragma unroll
        for (int c = 0; c < 4; ++c) {
            float4 g = *reinterpret_cast<const float4*>(gr + c * 256 + lane * 4);
            s += xv[c].x * g.x + xv[c].y * g.y + xv[c].z * g.z + xv[c].w * g.w;
        }
#pragma unroll
        for (int o = 32; o > 0; o >>= 1) s += __shfl_xor(s, o, 64);
        logit[e] = s + gb[e];
    }

    if (lane == 0) {
        int i1 = 0;
#pragma unroll
        for (int e = 1; e < NEXP; ++e) if (logit[e] > logit[i1]) i1 = e;
        int i2 = (i1 == 0) ? 1 : 0;
#pragma unroll
        for (int e = 0; e < NEXP; ++e)
            if (e != i1 && e != i2 && logit[e] > logit[i2]) i2 = e;
        float eb = expf(logit[i2] - logit[i1]);
        float wA = 1.f / (1.f + eb);
        float wB = eb / (1.f + eb);
        int p = atomicAdd(&cnt[i1], 1);
        toklist[i1 * T_TOK + p] = t; wlist[i1 * T_TOK + p] = wA;
        p = atomicAdd(&cnt[i2], 1);
        toklist[i2 * T_TOK + p] = t; wlist[i2 * T_TOK + p] = wB;
    }
}

// ---------------------------------------------------------------------------
// 2. 128-aligned exclusive prefix of per-expert counts
// ---------------------------------------------------------------------------
__global__ void offsets_kernel(const int* __restrict__ cnt, int* __restrict__ offs)
{
    if (threadIdx.x == 0) {
        int o = 0;
#pragma unroll
        for (int e = 0; e < NEXP; ++e) {
            offs[e] = o;
            o += ((cnt[e] + BM - 1) / BM) * BM;
        }
    }
}

// ---------------------------------------------------------------------------
// 3. Gather: Xp[slot] = bf16(x[token]); zero-fill tile padding rows.
// ---------------------------------------------------------------------------
__global__ __launch_bounds__(256) void gather_kernel(
    const float* __restrict__ x, const int* __restrict__ cnt,
    const int* __restrict__ offs, const int* __restrict__ toklist,
    unsigned short* __restrict__ Xp)
{
    const int b = blockIdx.x;
    const int e = b >> 12;
    const int i = b & 4095;
    const int c  = cnt[e];
    const int ca = ((c + BM - 1) >> 7) << 7;
    if (i >= ca) return;
    unsigned short* dst = Xp + (size_t)(offs[e] + i) * DIM;
    const int t4 = threadIdx.x * 4;
    ushort4 o;
    if (i < c) {
        const float* src = x + (size_t)toklist[e * T_TOK + i] * DIM;
        float4 v = *reinterpret_cast<const float4*>(src + t4);
        o.x = f2bf(v.x); o.y = f2bf(v.y); o.z = f2bf(v.z); o.w = f2bf(v.w);
    } else {
        o.x = 0; o.y = 0; o.z = 0; o.w = 0;
    }
    *reinterpret_cast<ushort4*>(dst + t4) = o;
}

// ---------------------------------------------------------------------------
// 4. Stage A: fused h1/h3 GEMM + SwiGLU -> act (bf16)
//    128x64 tile, BK=32, double-buffered LDS, ONE barrier/iter,
//    A staged via global_load_lds (async DMA), B via reg+cvt.
// ---------------------------------------------------------------------------
__global__ __launch_bounds__(256, 3) void stageA_kernel(
    const unsigned short* __restrict__ Xp, const float* __restrict__ w1,
    const float* __restrict__ w3, const int* __restrict__ cnt,
    const int* __restrict__ offs, unsigned short* __restrict__ act)
{
    const int e  = blockIdx.z;
    const int c  = cnt[e];
    const int mt = blockIdx.y;
    if (mt * BM >= c) return;
    const int nt = blockIdx.x;
    const size_t slot0 = (size_t)offs[e] + (size_t)mt * BM;
    const int n0 = nt * BN_A;

    __shared__ __align__(16) unsigned short As[2][BM * BK];     // 2 x 8 KB
    __shared__ __align__(16) unsigned short B1s[2][BN_A * BK];  // 2 x 4 KB
    __shared__ __align__(16) unsigned short B3s[2][BN_A * BK];  // 2 x 4 KB

    const int tid  = threadIdx.x;
    const int lane = tid & 63;
    const int wv   = tid >> 6;
    const int wm   = (wv & 1) * 64;
    const int wn   = (wv >> 1) * 32;
    const int quad = lane >> 4;
    const int r    = lane & 15;

    // --- A DMA addressing: wave wv owns rows [wv*32, wv*32+32), 2 issues/tile
    const int aRow = wv * 32 + (lane >> 2);            // +16 for issue 1
    const unsigned short* Adma = Xp + (slot0 + aRow) * DIM + (lane & 3) * 8;
    const int aLds0 = (wv * 32) * BK;                  // element offset, issue0
    const int aLds1 = (wv * 32 + 16) * BK;

    // --- B staging: thread -> row tid>>2 (0..63), 8 contiguous fp32
    const int brow = tid >> 2;
    const int bcol = (tid & 3) * 8;
    const float* B1g = w1 + ((size_t)e * FDIM + n0 + brow) * DIM + bcol;
    const float* B3g = w3 + ((size_t)e * FDIM + n0 + brow) * DIM + bcol;
    const int bofs = brow * BK + bcol;

    f32x4_t acc1[4][2];
    f32x4_t acc3[4][2];
#pragma unroll
    for (int i = 0; i < 4; ++i)
#pragma unroll
        for (int j = 0; j < 2; ++j) {
            acc1[i][j] = (f32x4_t){0.f, 0.f, 0.f, 0.f};
            acc3[i][j] = (f32x4_t){0.f, 0.f, 0.f, 0.f};
        }

    // ---- prologue: tile 0 into buffer 0
    GLD16(Adma,            &As[0][aLds0]);
    GLD16(Adma + 16 * DIM, &As[0][aLds1]);
    float4 p10 = *reinterpret_cast<const float4*>(B1g);
    float4 p11 = *reinterpret_cast<const float4*>(B1g + 4);
    float4 p30 = *reinterpret_cast<const float4*>(B3g);
    float4 p31 = *reinterpret_cast<const float4*>(B3g + 4);
    *reinterpret_cast<uint4*>(&B1s[0][bofs]) = pack8(p10, p11);
    *reinterpret_cast<uint4*>(&B3s[0][bofs]) = pack8(p30, p31);
    __syncthreads();

    int kk = 0;
    for (int k0 = 0; k0 < DIM; k0 += BK, kk ^= 1) {
        const int nxt = kk ^ 1;
        const bool more = (k0 + BK) < DIM;
        if (more) {
            // async DMA tile k+1 A -> other buffer; B loads -> regs
            GLD16(Adma + (k0 + BK),            &As[nxt][aLds0]);
            GLD16(Adma + (k0 + BK) + 16 * DIM, &As[nxt][aLds1]);
            p10 = *reinterpret_cast<const float4*>(B1g + k0 + BK);
            p11 = *reinterpret_cast<const float4*>(B1g + k0 + BK + 4);
            p30 = *reinterpret_cast<const float4*>(B3g + k0 + BK);
            p31 = *reinterpret_cast<const float4*>(B3g + k0 + BK + 4);
        }

        bf16x8_t af[4];
#pragma unroll
        for (int i = 0; i < 4; ++i)
            af[i] = *reinterpret_cast<const bf16x8_t*>(&As[kk][(wm + i * 16 + r) * BK + quad * 8]);
#pragma unroll
        for (int j = 0; j < 2; ++j) {
            bf16x8_t b1 = *reinterpret_cast<const bf16x8_t*>(&B1s[kk][(wn + j * 16 + r) * BK + quad * 8]);
            bf16x8_t b3 = *reinterpret_cast<const bf16x8_t*>(&B3s[kk][(wn + j * 16 + r) * BK + quad * 8]);
#pragma unroll
            for (int i = 0; i < 4; ++i) {
                acc1[i][j] = __builtin_amdgcn_mfma_f32_16x16x32_bf16(af[i], b1, acc1[i][j], 0, 0, 0);
                acc3[i][j] = __builtin_amdgcn_mfma_f32_16x16x32_bf16(af[i], b3, acc3[i][j], 0, 0, 0);
            }
        }

        if (more) {
            *reinterpret_cast<uint4*>(&B1s[nxt][bofs]) = pack8(p10, p11);
            *reinterpret_cast<uint4*>(&B3s[nxt][bofs]) = pack8(p30, p31);
        }
        __syncthreads();
    }

    unsigned short* abase = act + slot0 * FDIM + n0;
#pragma unroll
    for (int i = 0; i < 4; ++i)
#pragma unroll
        for (int j = 0; j < 2; ++j)
#pragma unroll
            for (int rr = 0; rr < 4; ++rr) {
                int m = wm + i * 16 + quad * 4 + rr;
                int n = wn + j * 16 + r;
                float h1 = acc1[i][j][rr];
                float h3 = acc3[i][j][rr];
                float sw = h1 / (1.f + __expf(-h1)) * h3;
                abase[(size_t)m * FDIM + n] = f2bf(sw);
            }
}

// ---------------------------------------------------------------------------
// 5. Stage B: out[tok] += cw * (act[slot] @ w2[e]^T)
//    128x128 tile, BK=32, K split in 2 (atomic combine), double-buffered,
//    one barrier/iter, A (act, bf16) via global_load_lds.
// ---------------------------------------------------------------------------
__global__ __launch_bounds__(256, 3) void stageB_kernel(
    const unsigned short* __restrict__ act, const float* __restrict__ w2,
    const int* __restrict__ cnt, const int* __restrict__ offs,
    const int* __restrict__ toklist, const float* __restrict__ wlist,
    float* __restrict__ out)
{
    const int e  = blockIdx.z & 7;
    const int ks = blockIdx.z >> 3;          // K-split half: 0 or 1
    const int c  = cnt[e];
    const int mt = blockIdx.y;
    if (mt * BM >= c) return;
    const int nt = blockIdx.x;               // 0..7 (D/128)
    const size_t slot0 = (size_t)offs[e] + (size_t)mt * BM;
    const int n0 = nt * BN_B;
    const int kbase = ks * (FDIM / 2);
    const int kend  = kbase + FDIM / 2;

    __shared__ __align__(16) unsigned short As[2][BM * BK];     // 2 x 8 KB
    __shared__ __align__(16) unsigned short Bs[2][BN_B * BK];   // 2 x 8 KB

    const int tid  = threadIdx.x;
    const int lane = tid & 63;
    const int wv   = tid >> 6;
    const int wm   = (wv & 1) * 64;
    const int wn   = (wv >> 1) * 64;
    const int quad = lane >> 4;
    const int r    = lane & 15;

    const int aRow = wv * 32 + (lane >> 2);
    const unsigned short* Adma = act + (slot0 + aRow) * FDIM + kbase + (lane & 3) * 8;
    const int aLds0 = (wv * 32) * BK;
    const int aLds1 = (wv * 32 + 16) * BK;

    // B: thread -> row tid>>1 (0..127), 16 contiguous fp32
    const int brow = tid >> 1;
    const int bcol = (tid & 1) * 16;
    const float* Bg = w2 + ((size_t)e * DIM + n0 + brow) * FDIM + kbase + bcol;
    const int bofs = brow * BK + bcol;

    f32x4_t acc[4][4];
#pragma unroll
    for (int i = 0; i < 4; ++i)
#pragma unroll
        for (int j = 0; j < 4; ++j) acc[i][j] = (f32x4_t){0.f, 0.f, 0.f, 0.f};

    // ---- prologue: tile 0
    GLD16(Adma,            &As[0][aLds0]);
    GLD16(Adma + 16 * FDIM, &As[0][aLds1]);
    float4 p0 = *reinterpret_cast<const float4*>(Bg);
    float4 p1 = *reinterpret_cast<const float4*>(Bg + 4);
    float4 p2 = *reinterpret_cast<const float4*>(Bg + 8);
    float4 p3 = *reinterpret_cast<const float4*>(Bg + 12);
    *reinterpret_cast<uint4*>(&Bs[0][bofs])     = pack8(p0, p1);
    *reinterpret_cast<uint4*>(&Bs[0][bofs + 8]) = pack8(p2, p3);
    __syncthreads();

    int kk = 0;
    for (int k0 = kbase; k0 < kend; k0 += BK, kk ^= 1) {
        const int nxt = kk ^ 1;
        const int kd = k0 - kbase;
        const bool more = (k0 + BK) < kend;
        if (more) {
            GLD16(Adma + kd + BK,             &As[nxt][aLds0]);
            GLD16(Adma + kd + BK + 16 * FDIM, &As[nxt][aLds1]);
            p0 = *reinterpret_cast<const float4*>(Bg + kd + BK);
            p1 = *reinterpret_cast<const float4*>(Bg + kd + BK + 4);
            p2 = *reinterpret_cast<const float4*>(Bg + kd + BK + 8);
            p3 = *reinterpret_cast<const float4*>(Bg + kd + BK + 12);
        }

        bf16x8_t af[4];
#pragma unroll
        for (int i = 0; i < 4; ++i)
            af[i] = *reinterpret_cast<const bf16x8_t*>(&As[kk][(wm + i * 16 + r) * BK + quad * 8]);
#pragma unroll
        for (int j = 0; j < 4; ++j) {
            bf16x8_t bf = *reinterpret_cast<const bf16x8_t*>(&Bs[kk][(wn + j * 16 + r) * BK + quad * 8]);
#pragma unroll
            for (int i = 0; i < 4; ++i)
                acc[i][j] = __builtin_amdgcn_mfma_f32_16x16x32_bf16(af[i], bf, acc[i][j], 0, 0, 0);
        }

        if (more) {
            *reinterpret_cast<uint4*>(&Bs[nxt][bofs])     = pack8(p0, p1);
            *reinterpret_cast<uint4*>(&Bs[nxt][bofs + 8]) = pack8(p2, p3);
        }
        __syncthreads();
    }

    const int row0 = mt * BM;
#pragma unroll
    for (int i = 0; i < 4; ++i)
#pragma unroll
        for (int rr = 0; rr < 4; ++rr) {
            int m = wm + i * 16 + quad * 4 + rr;
            int row = row0 + m;
            if (row < c) {
                int tok  = toklist[e * T_TOK + row];
                float wt = wlist[e * T_TOK + row];
                float* orow = out + (size_t)tok * DIM + n0;
#pragma unroll
                for (int j = 0; j < 4; ++j) {
                    int n = wn + j * 16 + r;
                    atomicAdd(&orow[n], wt * acc[i][j][rr]);
                }
            }
        }
}

// ---------------------------------------------------------------------------
extern "C" void kernel_launch(void* const* d_in, const int* in_sizes, int n_in,
                              void* d_out, int out_size, void* d_ws, size_t ws_size,
                              hipStream_t stream)
{
    (void)in_sizes; (void)n_in; (void)out_size; (void)ws_size;
    const float* x  = (const float*)d_in[0];
    const float* gw = (const float*)d_in[1];
    const float* gb = (const float*)d_in[2];
    const float* w1 = (const float*)d_in[3];
    const float* w3 = (const float*)d_in[4];
    const float* w2 = (const float*)d_in[5];
    float* out = (float*)d_out;

    char* ws = (char*)d_ws;
    unsigned short* Xp  = (unsigned short*)ws;                       // 9216*1024*2
    unsigned short* act = (unsigned short*)(ws + 18874368);          // 9216*4096*2
    int*   cnt     = (int*)(ws + 18874368 + 75497472);
    int*   offs    = cnt + 64;
    int*   toklist = cnt + 128;
    float* wlist   = (float*)(cnt + 128 + NEXP * T_TOK);

    hipMemsetAsync(cnt, 0, 64, stream);
    hipMemsetAsync(out, 0, (size_t)T_TOK * DIM * sizeof(float), stream);

    gate_kernel<<<T_TOK / 4, 256, 0, stream>>>(x, gw, gb, cnt, toklist, wlist);
    offsets_kernel<<<1, 64, 0, stream>>>(cnt, offs);
    gather_kernel<<<NEXP * T_TOK, 256, 0, stream>>>(x, cnt, offs, toklist, Xp);
    stageA_kernel<<<dim3(FDIM / BN_A, T_TOK / BM, NEXP), 256, 0, stream>>>(Xp, w1, w3, cnt, offs, act);
    stageB_kernel<<<dim3(DIM / BN_B, T_TOK / BM, NEXP * 2), 256, 0, stream>>>(act, w2, cnt, offs, toklist, wlist, out);
}

// Round 4
// 851.056 us; speedup vs baseline: 1.0777x; 1.0777x over previous
//
#include <hip/hip_runtime.h>
#include <hip/hip_bf16.h>

#define T_TOK 4096
#define DIM   1024
#define FDIM  4096
#define NEXP  8
#define BM    128
#define BN    128
#define BK    32

typedef __attribute__((ext_vector_type(8))) short bf16x8_t;   // 8 bf16 = 4 VGPR
typedef __attribute__((ext_vector_type(4))) float f32x4_t;    // MFMA C/D

// async global->LDS, 16B per lane; LDS dest = wave-uniform base + lane*16
#define GLD16(gp, lp) __builtin_amdgcn_global_load_lds( \
    (const __attribute__((address_space(1))) unsigned int*)(gp), \
    (__attribute__((address_space(3))) unsigned int*)(lp), 16, 0, 0)

__device__ __forceinline__ unsigned short f2bf(float f) {
    union { __hip_bfloat16 h; unsigned short u; } c;
    c.h = __float2bfloat16(f);
    return c.u;
}
__device__ __forceinline__ uint4 pack8(const float4& a, const float4& b) {
    union { unsigned short s[8]; uint4 v; } u;
    u.s[0] = f2bf(a.x); u.s[1] = f2bf(a.y); u.s[2] = f2bf(a.z); u.s[3] = f2bf(a.w);
    u.s[4] = f2bf(b.x); u.s[5] = f2bf(b.y); u.s[6] = f2bf(b.z); u.s[7] = f2bf(b.w);
    return u.v;
}

// ---------------------------------------------------------------------------
// 0. fp32 -> bf16 streaming convert (8 elems/thread)
// ---------------------------------------------------------------------------
__global__ __launch_bounds__(256) void convert_kernel(
    const float* __restrict__ src, unsigned short* __restrict__ dst, int n8)
{
    int i = blockIdx.x * 256 + threadIdx.x;
    if (i < n8) {
        const float4* s = reinterpret_cast<const float4*>(src) + (size_t)i * 2;
        float4 a = s[0], b = s[1];
        reinterpret_cast<uint4*>(dst)[i] = pack8(a, b);
    }
}

// ---------------------------------------------------------------------------
// 1. Gate: one wave per token. fp32 logits, top-2, renormalized weights.
// ---------------------------------------------------------------------------
__global__ __launch_bounds__(256) void gate_kernel(
    const float* __restrict__ x, const float* __restrict__ gw,
    const float* __restrict__ gb, int* __restrict__ cnt,
    int* __restrict__ toklist, float* __restrict__ wlist)
{
    const int lane = threadIdx.x & 63;
    const int wv   = threadIdx.x >> 6;
    const int t    = blockIdx.x * 4 + wv;
    const float* xr = x + (size_t)t * DIM;

    float4 xv[4];
#pragma unroll
    for (int c = 0; c < 4; ++c)
        xv[c] = *reinterpret_cast<const float4*>(xr + c * 256 + lane * 4);

    float logit[NEXP];
#pragma unroll
    for (int e = 0; e < NEXP; ++e) {
        const float* gr = gw + e * DIM;
        float s = 0.f;
#pragma unroll
        for (int c = 0; c < 4; ++c) {
            float4 g = *reinterpret_cast<const float4*>(gr + c * 256 + lane * 4);
            s += xv[c].x * g.x + xv[c].y * g.y + xv[c].z * g.z + xv[c].w * g.w;
        }
#pragma unroll
        for (int o = 32; o > 0; o >>= 1) s += __shfl_xor(s, o, 64);
        logit[e] = s + gb[e];
    }

    if (lane == 0) {
        int i1 = 0;
#pragma unroll
        for (int e = 1; e < NEXP; ++e) if (logit[e] > logit[i1]) i1 = e;
        int i2 = (i1 == 0) ? 1 : 0;
#pragma unroll
        for (int e = 0; e < NEXP; ++e)
            if (e != i1 && e != i2 && logit[e] > logit[i2]) i2 = e;
        float eb = expf(logit[i2] - logit[i1]);
        float wA = 1.f / (1.f + eb);
        float wB = eb / (1.f + eb);
        int p = atomicAdd(&cnt[i1], 1);
        toklist[i1 * T_TOK + p] = t; wlist[i1 * T_TOK + p] = wA;
        p = atomicAdd(&cnt[i2], 1);
        toklist[i2 * T_TOK + p] = t; wlist[i2 * T_TOK + p] = wB;
    }
}

// ---------------------------------------------------------------------------
// 2. 128-aligned exclusive prefix of per-expert counts
// ---------------------------------------------------------------------------
__global__ void offsets_kernel(const int* __restrict__ cnt, int* __restrict__ offs)
{
    if (threadIdx.x == 0) {
        int o = 0;
#pragma unroll
        for (int e = 0; e < NEXP; ++e) {
            offs[e] = o;
            o += ((cnt[e] + BM - 1) / BM) * BM;
        }
    }
}

// ---------------------------------------------------------------------------
// 3. Gather: Xp[slot] = bf16(x[token]); zero-fill tile padding rows.
// ---------------------------------------------------------------------------
__global__ __launch_bounds__(256) void gather_kernel(
    const float* __restrict__ x, const int* __restrict__ cnt,
    const int* __restrict__ offs, const int* __restrict__ toklist,
    unsigned short* __restrict__ Xp)
{
    const int b = blockIdx.x;
    const int e = b >> 12;
    const int i = b & 4095;
    const int c  = cnt[e];
    const int ca = ((c + BM - 1) >> 7) << 7;
    if (i >= ca) return;
    unsigned short* dst = Xp + (size_t)(offs[e] + i) * DIM;
    const int t4 = threadIdx.x * 4;
    ushort4 o;
    if (i < c) {
        const float* src = x + (size_t)toklist[e * T_TOK + i] * DIM;
        float4 v = *reinterpret_cast<const float4*>(src + t4);
        o.x = f2bf(v.x); o.y = f2bf(v.y); o.z = f2bf(v.z); o.w = f2bf(v.w);
    } else {
        o.x = 0; o.y = 0; o.z = 0; o.w = 0;
    }
    *reinterpret_cast<ushort4*>(dst + t4) = o;
}

// ---------------------------------------------------------------------------
// 4. Stage A: fused h1/h3 GEMM + SwiGLU -> act (bf16)
//    m97 structure: 128x128 tile, BK=32, single-buffered LDS, 2 barriers,
//    ALL tiles staged via global_load_lds width=16. Dual accumulators.
// ---------------------------------------------------------------------------
__global__ __launch_bounds__(256, 2) void stageA_kernel(
    const unsigned short* __restrict__ Xp, const unsigned short* __restrict__ w1b,
    const unsigned short* __restrict__ w3b, const int* __restrict__ cnt,
    const int* __restrict__ offs, unsigned short* __restrict__ act)
{
    const int e  = blockIdx.z;
    const int c  = cnt[e];
    const int mt = blockIdx.y;
    if (mt * BM >= c) return;
    const int nt = blockIdx.x;               // 0..31 (F/128)
    const size_t slot0 = (size_t)offs[e] + (size_t)mt * BM;
    const int n0 = nt * BN;

    __shared__ __align__(16) unsigned short As[BM * BK];    // 8 KB
    __shared__ __align__(16) unsigned short B1s[BN * BK];   // 8 KB
    __shared__ __align__(16) unsigned short B3s[BN * BK];   // 8 KB

    const int tid  = threadIdx.x;
    const int lane = tid & 63;
    const int wv   = tid >> 6;
    const int wm   = (wv & 1) * 64;
    const int wn   = (wv >> 1) * 64;
    const int quad = lane >> 4;
    const int r    = lane & 15;

    // DMA: wave wv owns rows [wv*32, wv*32+32) of each tile, 2 issues each
    const int dRow = wv * 32 + (lane >> 2);
    const unsigned short* Adma  = Xp  + (slot0 + dRow) * DIM + (lane & 3) * 8;
    const unsigned short* B1dma = w1b + ((size_t)e * FDIM + n0 + dRow) * DIM + (lane & 3) * 8;
    const unsigned short* B3dma = w3b + ((size_t)e * FDIM + n0 + dRow) * DIM + (lane & 3) * 8;
    const int lds0 = (wv * 32) * BK;
    const int lds1 = (wv * 32 + 16) * BK;

    f32x4_t acc1[4][4];
    f32x4_t acc3[4][4];
#pragma unroll
    for (int i = 0; i < 4; ++i)
#pragma unroll
        for (int j = 0; j < 4; ++j) {
            acc1[i][j] = (f32x4_t){0.f, 0.f, 0.f, 0.f};
            acc3[i][j] = (f32x4_t){0.f, 0.f, 0.f, 0.f};
        }

    for (int k0 = 0; k0 < DIM; k0 += BK) {
        __syncthreads();
        GLD16(Adma + k0,             &As[lds0]);
        GLD16(Adma + k0 + 16 * DIM,  &As[lds1]);
        GLD16(B1dma + k0,            &B1s[lds0]);
        GLD16(B1dma + k0 + 16 * DIM, &B1s[lds1]);
        GLD16(B3dma + k0,            &B3s[lds0]);
        GLD16(B3dma + k0 + 16 * DIM, &B3s[lds1]);
        __syncthreads();

        bf16x8_t af[4];
#pragma unroll
        for (int i = 0; i < 4; ++i)
            af[i] = *reinterpret_cast<const bf16x8_t*>(&As[(wm + i * 16 + r) * BK + quad * 8]);
#pragma unroll
        for (int j = 0; j < 4; ++j) {
            bf16x8_t b1 = *reinterpret_cast<const bf16x8_t*>(&B1s[(wn + j * 16 + r) * BK + quad * 8]);
            bf16x8_t b3 = *reinterpret_cast<const bf16x8_t*>(&B3s[(wn + j * 16 + r) * BK + quad * 8]);
#pragma unroll
            for (int i = 0; i < 4; ++i) {
                acc1[i][j] = __builtin_amdgcn_mfma_f32_16x16x32_bf16(af[i], b1, acc1[i][j], 0, 0, 0);
                acc3[i][j] = __builtin_amdgcn_mfma_f32_16x16x32_bf16(af[i], b3, acc3[i][j], 0, 0, 0);
            }
        }
    }

    unsigned short* abase = act + slot0 * FDIM + n0;
#pragma unroll
    for (int i = 0; i < 4; ++i)
#pragma unroll
        for (int j = 0; j < 4; ++j)
#pragma unroll
            for (int rr = 0; rr < 4; ++rr) {
                int m = wm + i * 16 + quad * 4 + rr;
                int n = wn + j * 16 + r;
                float h1 = acc1[i][j][rr];
                float h3 = acc3[i][j][rr];
                float sw = h1 / (1.f + __expf(-h1)) * h3;
                abase[(size_t)m * FDIM + n] = f2bf(sw);
            }
}

// ---------------------------------------------------------------------------
// 5. Stage B: out[tok] += cw * (act[slot] @ w2[e]^T)
//    m97 structure, 128x128 tile, K split in 2, atomic combine epilogue.
// ---------------------------------------------------------------------------
__global__ __launch_bounds__(256, 3) void stageB_kernel(
    const unsigned short* __restrict__ act, const unsigned short* __restrict__ w2b,
    const int* __restrict__ cnt, const int* __restrict__ offs,
    const int* __restrict__ toklist, const float* __restrict__ wlist,
    float* __restrict__ out)
{
    const int e  = blockIdx.z & 7;
    const int ks = blockIdx.z >> 3;
    const int c  = cnt[e];
    const int mt = blockIdx.y;
    if (mt * BM >= c) return;
    const int nt = blockIdx.x;               // 0..7 (D/128)
    const size_t slot0 = (size_t)offs[e] + (size_t)mt * BM;
    const int n0 = nt * BN;
    const int kbase = ks * (FDIM / 2);

    __shared__ __align__(16) unsigned short As[BM * BK];    // 8 KB
    __shared__ __align__(16) unsigned short Bs[BN * BK];    // 8 KB

    const int tid  = threadIdx.x;
    const int lane = tid & 63;
    const int wv   = tid >> 6;
    const int wm   = (wv & 1) * 64;
    const int wn   = (wv >> 1) * 64;
    const int quad = lane >> 4;
    const int r    = lane & 15;

    const int dRow = wv * 32 + (lane >> 2);
    const unsigned short* Adma = act + (slot0 + dRow) * FDIM + kbase + (lane & 3) * 8;
    const unsigned short* Bdma = w2b + ((size_t)e * DIM + n0 + dRow) * FDIM + kbase + (lane & 3) * 8;
    const int lds0 = (wv * 32) * BK;
    const int lds1 = (wv * 32 + 16) * BK;

    f32x4_t acc[4][4];
#pragma unroll
    for (int i = 0; i < 4; ++i)
#pragma unroll
        for (int j = 0; j < 4; ++j) acc[i][j] = (f32x4_t){0.f, 0.f, 0.f, 0.f};

    for (int kd = 0; kd < FDIM / 2; kd += BK) {
        __syncthreads();
        GLD16(Adma + kd,             &As[lds0]);
        GLD16(Adma + kd + 16 * FDIM, &As[lds1]);
        GLD16(Bdma + kd,             &Bs[lds0]);
        GLD16(Bdma + kd + 16 * FDIM, &Bs[lds1]);
        __syncthreads();

        bf16x8_t af[4];
#pragma unroll
        for (int i = 0; i < 4; ++i)
            af[i] = *reinterpret_cast<const bf16x8_t*>(&As[(wm + i * 16 + r) * BK + quad * 8]);
#pragma unroll
        for (int j = 0; j < 4; ++j) {
            bf16x8_t bf = *reinterpret_cast<const bf16x8_t*>(&Bs[(wn + j * 16 + r) * BK + quad * 8]);
#pragma unroll
            for (int i = 0; i < 4; ++i)
                acc[i][j] = __builtin_amdgcn_mfma_f32_16x16x32_bf16(af[i], bf, acc[i][j], 0, 0, 0);
        }
    }

    const int row0 = mt * BM;
#pragma unroll
    for (int i = 0; i < 4; ++i)
#pragma unroll
        for (int rr = 0; rr < 4; ++rr) {
            int m = wm + i * 16 + quad * 4 + rr;
            int row = row0 + m;
            if (row < c) {
                int tok  = toklist[e * T_TOK + row];
                float wt = wlist[e * T_TOK + row];
                float* orow = out + (size_t)tok * DIM + n0;
#pragma unroll
                for (int j = 0; j < 4; ++j) {
                    int n = wn + j * 16 + r;
                    atomicAdd(&orow[n], wt * acc[i][j][rr]);
                }
            }
        }
}

// ---------------------------------------------------------------------------
extern "C" void kernel_launch(void* const* d_in, const int* in_sizes, int n_in,
                              void* d_out, int out_size, void* d_ws, size_t ws_size,
                              hipStream_t stream)
{
    (void)in_sizes; (void)n_in; (void)out_size; (void)ws_size;
    const float* x  = (const float*)d_in[0];
    const float* gw = (const float*)d_in[1];
    const float* gb = (const float*)d_in[2];
    const float* w1 = (const float*)d_in[3];
    const float* w3 = (const float*)d_in[4];
    const float* w2 = (const float*)d_in[5];
    float* out = (float*)d_out;

    // ws layout (~296 MB)
    char* ws = (char*)d_ws;
    unsigned short* Xp   = (unsigned short*)ws;                        // 18,874,368
    unsigned short* act  = (unsigned short*)(ws + 18874368);           // 75,497,472
    unsigned short* w1b  = (unsigned short*)(ws + 94371840);           // 67,108,864
    unsigned short* w3b  = (unsigned short*)(ws + 161480704);          // 67,108,864
    unsigned short* w2b  = (unsigned short*)(ws + 228589568);          // 67,108,864
    int*   cnt     = (int*)(ws + 295698432);
    int*   offs    = cnt + 64;
    int*   toklist = cnt + 128;
    float* wlist   = (float*)(cnt + 128 + NEXP * T_TOK);

    hipMemsetAsync(cnt, 0, 64, stream);
    hipMemsetAsync(out, 0, (size_t)T_TOK * DIM * sizeof(float), stream);

    const int n8 = NEXP * FDIM * DIM / 8;   // 4,194,304 per tensor
    convert_kernel<<<n8 / 256, 256, 0, stream>>>(w1, w1b, n8);
    convert_kernel<<<n8 / 256, 256, 0, stream>>>(w3, w3b, n8);
    convert_kernel<<<n8 / 256, 256, 0, stream>>>(w2, w2b, n8);

    gate_kernel<<<T_TOK / 4, 256, 0, stream>>>(x, gw, gb, cnt, toklist, wlist);
    offsets_kernel<<<1, 64, 0, stream>>>(cnt, offs);
    gather_kernel<<<NEXP * T_TOK, 256, 0, stream>>>(x, cnt, offs, toklist, Xp);
    stageA_kernel<<<dim3(FDIM / BN, T_TOK / BM, NEXP), 256, 0, stream>>>(Xp, w1b, w3b, cnt, offs, act);
    stageB_kernel<<<dim3(DIM / BN, T_TOK / BM, NEXP * 2), 256, 0, stream>>>(act, w2b, cnt, offs, toklist, wlist, out);
}